// Round 16
// baseline (49.897 us; speedup 1.0000x reference)
//
#include <hip/hip_runtime.h>

#define DIM 4096
#define R 8
// ws layout: G (8x8) at ws[0..63]; P (4096 x 8) at ws+64
#define P_OFF 64
#define PLS_STRIDE 36   // pad 32->36 floats: 16B-aligned, spreads banks

// ---------------------------------------------------------------------------
// K1: blocks 0,1 = Gram rows 0..3 / 4..7 (proven early-return path).
// Blocks 2..1025: coalesced dot, 4 rows x ALL 4096 cols per block.
// Objective (R13-R15 model): minimize TOTAL thread-instructions
// (= blocks x 256 x per-thread), since the replay-start window throttles
// chip-wide instruction issue (~10M thread-instr/us) while HBM runs full
// speed. 1024 blocks x ~740 instr = ~190M, vs R14's 272M / R15's 398M.
// ---------------------------------------------------------------------------
__global__ __launch_bounds__(256) void dot_kernel(const float* __restrict__ W,
                                                  const float* __restrict__ A,
                                                  float* __restrict__ G,
                                                  float* __restrict__ P) {
    __shared__ float red[4][32];                  // gram path only
    __shared__ float pls[256 * PLS_STRIDE];       // 36 KB: per-thread p[4][8]
    __shared__ float s2[8][33];                   // stage-2 partials (padded)

    const int t = threadIdx.x;
    const int wave = t >> 6, lane = t & 63;
    const int bid = blockIdx.x;
    const float4* A4 = (const float4*)A;

    if (bid < 2) {
        // ---- Gram path (R7 verbatim): block 0 -> G rows 0..3, block 1 -> 4..7
        const int hi = bid * 4;
        float p[4][R];
#pragma unroll
        for (int r = 0; r < 4; ++r)
#pragma unroll
            for (int k = 0; k < R; ++k) p[r][k] = 0.f;

        for (int it = 0; it < DIM / 256; ++it) {
            const int j = it * 256 + t;
            float4 alo = A4[j * 2 + 0];
            float4 ahi = A4[j * 2 + 1];
            float u[R] = {alo.x, alo.y, alo.z, alo.w, ahi.x, ahi.y, ahi.z, ahi.w};
            float wv0 = hi ? u[4] : u[0];
            float wv1 = hi ? u[5] : u[1];
            float wv2 = hi ? u[6] : u[2];
            float wv3 = hi ? u[7] : u[3];
#pragma unroll
            for (int k = 0; k < R; ++k) {
                p[0][k] += wv0 * u[k];
                p[1][k] += wv1 * u[k];
                p[2][k] += wv2 * u[k];
                p[3][k] += wv3 * u[k];
            }
        }

#pragma unroll
        for (int r = 0; r < 4; ++r)
#pragma unroll
            for (int k = 0; k < R; ++k) {
                float v = p[r][k];
#pragma unroll
                for (int off = 32; off >= 1; off >>= 1) v += __shfl_xor(v, off, 64);
                p[r][k] = v;
            }

#pragma unroll
        for (int i = 0; i < 32; ++i)
            if (lane == i) red[wave][i] = p[i / R][i % R];
        __syncthreads();

        if (t < 32) {
            float v = red[0][t] + red[1][t] + red[2][t] + red[3][t];
            G[(hi + (t >> 3)) * 8 + (t & 7)] = v;
        }
        return;
    }

    // ---- dot path: 4 rows x 4096 cols. wave w owns j in [w*1024, +1024).
    const int row0 = (bid - 2) * 4;
    const float* Wr = W + (size_t)row0 * DIM;
    const int jbase = wave * 1024 + lane;

    float p[4][R];
#pragma unroll
    for (int r = 0; r < 4; ++r)
#pragma unroll
        for (int k = 0; k < R; ++k) p[r][k] = 0.f;

#pragma unroll
    for (int it = 0; it < 16; ++it) {
        const int j = jbase + it * 64;
        float4 alo = A4[j * 2 + 0];              // lane-contiguous
        float4 ahi = A4[j * 2 + 1];
        float w0 = Wr[j];                        // coalesced scalar streams
        float w1 = Wr[DIM + j];
        float w2 = Wr[2 * DIM + j];
        float w3 = Wr[3 * DIM + j];
        float u[R] = {alo.x, alo.y, alo.z, alo.w, ahi.x, ahi.y, ahi.z, ahi.w};
#pragma unroll
        for (int k = 0; k < R; ++k) {
            p[0][k] += w0 * u[k];
            p[1][k] += w1 * u[k];
            p[2][k] += w2 * u[k];
            p[3][k] += w3 * u[k];
        }
    }

    // ---- tail (R14-proven): dump p[4][8] to LDS, 2-stage tree
    float4* prow = (float4*)&pls[t * PLS_STRIDE];
#pragma unroll
    for (int r = 0; r < 4; ++r) {
        prow[r * 2 + 0] = make_float4(p[r][0], p[r][1], p[r][2], p[r][3]);
        prow[r * 2 + 1] = make_float4(p[r][4], p[r][5], p[r][6], p[r][7]);
    }
    __syncthreads();

    {
        const int g = t >> 5, c = t & 31;
        float s = 0.f;
#pragma unroll
        for (int i = 0; i < 32; ++i) s += pls[(g * 32 + i) * PLS_STRIDE + c];
        s2[g][c] = s;
    }
    __syncthreads();

    if (t < 32) {
        float v = 0.f;
#pragma unroll
        for (int g = 0; g < 8; ++g) v += s2[g][t];
        const int r = t >> 3, k = t & 7;
        P[(size_t)(row0 + r) * R + k] = v;
    }
}

// ---------------------------------------------------------------------------
// K2: out = W - (2 P G^{-1}) . A^T.  2048 blocks x 256 threads
// (R4/R7-proven body). Wave 0 inverts G hidden under A-fragment loads.
// ---------------------------------------------------------------------------
__global__ __launch_bounds__(256, 4) void apply_kernel(const float* __restrict__ W,
                                                       const float* __restrict__ A,
                                                       const float* __restrict__ G,
                                                       const float* __restrict__ P,
                                                       float* __restrict__ out) {
    __shared__ float sb[64];       // Sinv = G^{-1}
    __shared__ float tsh[32][8];

    const int t = threadIdx.x;
    const int wave = t >> 6, lane = t & 63;
    const int bid = blockIdx.x;
    const int tr = bid >> 4;        // 128 row-tiles of 32
    const int tc = bid & 15;        // 16 col-tiles of 256
    const int c4 = tc * 64 + lane;  // float4 column index [0,1024)

    const float4* A4 = (const float4*)A;
    const float4* W4 = (const float4*)W;
    float4* O4 = (float4*)out;

    float4 alo[4], ahi[4];
#pragma unroll
    for (int jj = 0; jj < 4; ++jj) {
        const int j = c4 * 4 + jj;
        alo[jj] = A4[j * 2 + 0];
        ahi[jj] = A4[j * 2 + 1];
    }

    if (wave == 0) {
        const int r_ = lane >> 3, c_ = lane & 7;
        float M = G[lane];
        float E = (r_ == c_) ? 1.f : 0.f;
        // Gauss-Jordan, no pivoting (G is SPD, kappa ~ 1)
#pragma unroll
        for (int k = 0; k < R; ++k) {
            float piv  = __shfl(M, k * 8 + k, 64);
            float pinv = 1.0f / piv;
            float Mkc  = __shfl(M, k * 8 + c_, 64) * pinv;
            float Ekc  = __shfl(E, k * 8 + c_, 64) * pinv;
            float Mrk  = __shfl(M, r_ * 8 + k, 64);
            bool  isk  = (r_ == k);
            M = isk ? Mkc : (M - Mrk * Mkc);
            E = isk ? Ekc : (E - Mrk * Ekc);
        }
        sb[lane] = E;
    }
    __syncthreads();

    {
        const int r = t >> 3, k = t & 7;
        const int row = tr * 32 + r;
        const float* q = &P[(size_t)row * R];
        float a = 0.f;
#pragma unroll
        for (int m = 0; m < R; ++m) a += sb[k * 8 + m] * q[m];
        tsh[r][k] = 2.0f * a;
    }
    __syncthreads();

    const int lr0 = wave * 8;
#pragma unroll
    for (int rr = 0; rr < 8; ++rr) {
        const int row = tr * 32 + lr0 + rr;
        const float* tv = &tsh[lr0 + rr][0];
        float t0 = tv[0], t1 = tv[1], t2 = tv[2], t3 = tv[3];
        float t4 = tv[4], t5 = tv[5], t6 = tv[6], t7 = tv[7];
        float4 w4 = W4[(size_t)row * (DIM / 4) + c4];
        float o[4];
#pragma unroll
        for (int jj = 0; jj < 4; ++jj) {
            float d = t0 * alo[jj].x + t1 * alo[jj].y +
                      t2 * alo[jj].z + t3 * alo[jj].w +
                      t4 * ahi[jj].x + t5 * ahi[jj].y +
                      t6 * ahi[jj].z + t7 * ahi[jj].w;
            o[jj] = ((const float*)&w4)[jj] - d;
        }
        O4[(size_t)row * (DIM / 4) + c4] = make_float4(o[0], o[1], o[2], o[3]);
    }
}

extern "C" void kernel_launch(void* const* d_in, const int* in_sizes, int n_in,
                              void* d_out, int out_size, void* d_ws, size_t ws_size,
                              hipStream_t stream) {
    const float* W = (const float*)d_in[0];    // [4096][4096] f32
    const float* A = (const float*)d_in[1];    // [4096][8]    f32
    float* out = (float*)d_out;                // [4096][4096] f32
    float* G = (float*)d_ws;                   // 64 floats (8x8 Gram)
    float* P = (float*)d_ws + P_OFF;           // 4096*8 floats

    dot_kernel<<<(DIM / 4) + 2, 256, 0, stream>>>(W, A, G, P);
    apply_kernel<<<2048, 256, 0, stream>>>(W, A, G, P, out);
}

// Round 17
// 43.731 us; speedup vs baseline: 1.1410x; 1.1410x over previous
//
#include <hip/hip_runtime.h>

#define DIM 4096
#define R 8
// ws layout: G (8x8) at ws[0..63]; P4 (4096 rows x 4 quarters x 8) at ws+64
#define P_OFF 64
#define PLS_STRIDE 36   // pad 32->36 floats: 16B-aligned, spreads banks

// ---------------------------------------------------------------------------
// K1: blocks 0,1 = Gram rows 0..3 / 4..7 (R7/R13-proven early-return path).
// Blocks 2..4097: instruction-diet dot. 4 rows x 1024-col quarter per block.
// Empirical optimum from the R13-R16 sweep: 4096 blocks x ~260 instr/thread
// balances ramp-window chip-wide instruction issue vs TLP (44.0 us total;
// 1024blk=49.9, 2048blk=59.8, 8192blk=49.5).
// ---------------------------------------------------------------------------
__global__ __launch_bounds__(256) void dot_kernel(const float* __restrict__ W,
                                                  const float* __restrict__ A,
                                                  float* __restrict__ G,
                                                  float* __restrict__ P4) {
    __shared__ float red[4][32];                  // gram path only
    __shared__ float pls[256 * PLS_STRIDE];       // 36 KB: per-thread p[4][8]
    __shared__ float s2[8][33];                   // stage-2 partials (padded)

    const int t = threadIdx.x;
    const int wave = t >> 6, lane = t & 63;
    const int bid = blockIdx.x;
    const float4* A4 = (const float4*)A;

    if (bid < 2) {
        // ---- Gram path (R7 verbatim): block 0 -> G rows 0..3, block 1 -> 4..7
        const int hi = bid * 4;
        float p[4][R];
#pragma unroll
        for (int r = 0; r < 4; ++r)
#pragma unroll
            for (int k = 0; k < R; ++k) p[r][k] = 0.f;

        for (int it = 0; it < DIM / 256; ++it) {
            const int j = it * 256 + t;
            float4 alo = A4[j * 2 + 0];
            float4 ahi = A4[j * 2 + 1];
            float u[R] = {alo.x, alo.y, alo.z, alo.w, ahi.x, ahi.y, ahi.z, ahi.w};
            float wv0 = hi ? u[4] : u[0];
            float wv1 = hi ? u[5] : u[1];
            float wv2 = hi ? u[6] : u[2];
            float wv3 = hi ? u[7] : u[3];
#pragma unroll
            for (int k = 0; k < R; ++k) {
                p[0][k] += wv0 * u[k];
                p[1][k] += wv1 * u[k];
                p[2][k] += wv2 * u[k];
                p[3][k] += wv3 * u[k];
            }
        }

#pragma unroll
        for (int r = 0; r < 4; ++r)
#pragma unroll
            for (int k = 0; k < R; ++k) {
                float v = p[r][k];
#pragma unroll
                for (int off = 32; off >= 1; off >>= 1) v += __shfl_xor(v, off, 64);
                p[r][k] = v;
            }

#pragma unroll
        for (int i = 0; i < 32; ++i)
            if (lane == i) red[wave][i] = p[i / R][i % R];
        __syncthreads();

        if (t < 32) {
            float v = red[0][t] + red[1][t] + red[2][t] + red[3][t];
            G[(hi + (t >> 3)) * 8 + (t & 7)] = v;
        }
        return;
    }

    // ---- diet dot path: 4 rows x 1024-col quarter per block.
    const int db = bid - 2;          // 0..4095
    const int row0 = (db >> 2) * 4;
    const int cq = db & 3;           // column quarter
    const float* Wr = W + (size_t)row0 * DIM;
    const int jbase = cq * 1024 + wave * 256 + lane;

    float p[4][R];
#pragma unroll
    for (int r = 0; r < 4; ++r)
#pragma unroll
        for (int k = 0; k < R; ++k) p[r][k] = 0.f;

#pragma unroll
    for (int it = 0; it < 4; ++it) {
        const int j = jbase + it * 64;
        float4 alo = A4[j * 2 + 0];              // lane-contiguous
        float4 ahi = A4[j * 2 + 1];
        float w0 = Wr[j];                        // coalesced scalar streams
        float w1 = Wr[DIM + j];
        float w2 = Wr[2 * DIM + j];
        float w3 = Wr[3 * DIM + j];
        float u[R] = {alo.x, alo.y, alo.z, alo.w, ahi.x, ahi.y, ahi.z, ahi.w};
#pragma unroll
        for (int k = 0; k < R; ++k) {
            p[0][k] += w0 * u[k];
            p[1][k] += w1 * u[k];
            p[2][k] += w2 * u[k];
            p[3][k] += w3 * u[k];
        }
    }

    // ---- no butterfly: dump p[4][8] to LDS (8 x ds_write_b128)
    float4* prow = (float4*)&pls[t * PLS_STRIDE];
#pragma unroll
    for (int r = 0; r < 4; ++r) {
        prow[r * 2 + 0] = make_float4(p[r][0], p[r][1], p[r][2], p[r][3]);
        prow[r * 2 + 1] = make_float4(p[r][4], p[r][5], p[r][6], p[r][7]);
    }
    __syncthreads();

    // stage 1: thread (g = t>>5, c = t&31) sums rows g*32..g*32+31 of col c
    {
        const int g = t >> 5, c = t & 31;
        float s = 0.f;
#pragma unroll
        for (int i = 0; i < 32; ++i) s += pls[(g * 32 + i) * PLS_STRIDE + c];
        s2[g][c] = s;
    }
    __syncthreads();

    // stage 2: t<32 sums the 8 group-partials, stores P4 slot
    if (t < 32) {
        float v = 0.f;
#pragma unroll
        for (int g = 0; g < 8; ++g) v += s2[g][t];
        const int r = t >> 3, k = t & 7;
        P4[(((size_t)(row0 + r)) * 4 + cq) * R + k] = v;
    }
}

// ---------------------------------------------------------------------------
// K2: out = W - (2 (P0+P1+P2+P3) G^{-1}) . A^T.  2048 blocks x 256 threads
// (R7/R13 verbatim apart from the 4-partial sum).
// ---------------------------------------------------------------------------
__global__ __launch_bounds__(256, 4) void apply_kernel(const float* __restrict__ W,
                                                       const float* __restrict__ A,
                                                       const float* __restrict__ G,
                                                       const float* __restrict__ P4,
                                                       float* __restrict__ out) {
    __shared__ float sb[64];       // Sinv = G^{-1}
    __shared__ float tsh[32][8];

    const int t = threadIdx.x;
    const int wave = t >> 6, lane = t & 63;
    const int bid = blockIdx.x;
    const int tr = bid >> 4;        // 128 row-tiles of 32
    const int tc = bid & 15;        // 16 col-tiles of 256
    const int c4 = tc * 64 + lane;  // float4 column index [0,1024)

    const float4* A4 = (const float4*)A;
    const float4* W4 = (const float4*)W;
    float4* O4 = (float4*)out;

    float4 alo[4], ahi[4];
#pragma unroll
    for (int jj = 0; jj < 4; ++jj) {
        const int j = c4 * 4 + jj;
        alo[jj] = A4[j * 2 + 0];
        ahi[jj] = A4[j * 2 + 1];
    }

    if (wave == 0) {
        const int r_ = lane >> 3, c_ = lane & 7;
        float M = G[lane];
        float E = (r_ == c_) ? 1.f : 0.f;
        // Gauss-Jordan, no pivoting (G is SPD, kappa ~ 1)
#pragma unroll
        for (int k = 0; k < R; ++k) {
            float piv  = __shfl(M, k * 8 + k, 64);
            float pinv = 1.0f / piv;
            float Mkc  = __shfl(M, k * 8 + c_, 64) * pinv;
            float Ekc  = __shfl(E, k * 8 + c_, 64) * pinv;
            float Mrk  = __shfl(M, r_ * 8 + k, 64);
            bool  isk  = (r_ == k);
            M = isk ? Mkc : (M - Mrk * Mkc);
            E = isk ? Ekc : (E - Mrk * Ekc);
        }
        sb[lane] = E;
    }
    __syncthreads();

    {
        const int r = t >> 3, k = t & 7;
        const int row = tr * 32 + r;
        const float* q = &P4[(size_t)row * 4 * R];
        float a = 0.f;
#pragma unroll
        for (int m = 0; m < R; ++m)
            a += sb[k * 8 + m] * (q[m] + q[R + m] + q[2 * R + m] + q[3 * R + m]);
        tsh[r][k] = 2.0f * a;
    }
    __syncthreads();

    const int lr0 = wave * 8;
#pragma unroll
    for (int rr = 0; rr < 8; ++rr) {
        const int row = tr * 32 + lr0 + rr;
        const float* tv = &tsh[lr0 + rr][0];
        float t0 = tv[0], t1 = tv[1], t2 = tv[2], t3 = tv[3];
        float t4 = tv[4], t5 = tv[5], t6 = tv[6], t7 = tv[7];
        float4 w4 = W4[(size_t)row * (DIM / 4) + c4];
        float o[4];
#pragma unroll
        for (int jj = 0; jj < 4; ++jj) {
            float d = t0 * alo[jj].x + t1 * alo[jj].y +
                      t2 * alo[jj].z + t3 * alo[jj].w +
                      t4 * ahi[jj].x + t5 * ahi[jj].y +
                      t6 * ahi[jj].z + t7 * ahi[jj].w;
            o[jj] = ((const float*)&w4)[jj] - d;
        }
        O4[(size_t)row * (DIM / 4) + c4] = make_float4(o[0], o[1], o[2], o[3]);
    }
}

extern "C" void kernel_launch(void* const* d_in, const int* in_sizes, int n_in,
                              void* d_out, int out_size, void* d_ws, size_t ws_size,
                              hipStream_t stream) {
    const float* W = (const float*)d_in[0];    // [4096][4096] f32
    const float* A = (const float*)d_in[1];    // [4096][8]    f32
    float* out = (float*)d_out;                // [4096][4096] f32
    float* G = (float*)d_ws;                   // 64 floats (8x8 Gram)
    float* P4 = (float*)d_ws + P_OFF;          // 4096*4*8 floats

    dot_kernel<<<4 * (DIM / 4) + 2, 256, 0, stream>>>(W, A, G, P4);
    apply_kernel<<<2048, 256, 0, stream>>>(W, A, G, P4, out);
}